// Round 17
// baseline (247.794 us; speedup 1.0000x reference)
//
#include <hip/hip_runtime.h>

// 3x3 conv (sparse weights treated dense), NCHW/OIHW, stride1 pad1, fp32 I/O.
// B=32, CIN=COUT=256, H=W=56.
//
// R17 = R16 with the A path moved from LDS to REGISTERS (2-phase-ahead
// global->VGPR loads from L2-resident wb2). R16 counters showed the LDS
// read pipe ~80% busy (9 b128/tap for 68 cyc of MFMA) — the binding pipe.
//  - LDS now holds ONLY X: 16KB single rolling buffer (R16 scheme).
//  - A: 2 parity reg-buffers aA/aB (2 taps x 2 frags x short8 = 16 VGPR each).
//    Phase p, after its MFMAs (anti-dep pins order), loads A(p+2) into its
//    own parity buffer. All indices compile-time static.
//  - FIFO vmcnt ledger (A batches 4,4,4,4,2; X2 at q2/q4 tails), hand-walked:
//    head waits {q0:6, q1:4, q2:4, q3:4, q4:6}; never 0 mid-loop.
//  - m2n7 wave, 128-cout blocks, grid 1792, swizzle/epilogue: R16 verbatim.

typedef __attribute__((ext_vector_type(8))) short short8;
typedef __attribute__((ext_vector_type(4))) float f32x4;
typedef __attribute__((ext_vector_type(4))) int i32x4;

constexpr int BB = 32, CIN = 256, COUT = 256, H = 56, W = 56, HW = H * W;
constexpr int HP = 58, WP = 58;

constexpr size_t XP_ELEMS = (size_t)BB * HP * WP * CIN;
constexpr size_t WB_ELEMS = (size_t)COUT * 9 * CIN;
constexpr size_t WS_NEEDED = (XP_ELEMS + WB_ELEMS) * 2;

__device__ __forceinline__ ushort f2bf(float f) {
    unsigned x = __float_as_uint(f);
    unsigned r = (x + 0x7FFFu + ((x >> 16) & 1u)) >> 16;   // RNE
    return (ushort)r;
}

// ---------------- prep kernels (unchanged) ----------------

__global__ __launch_bounds__(256)
void prep_xp(const float* __restrict__ x, ushort* __restrict__ xp) {
    const int bi = blockIdx.x;            // b*58 + padded row i
    const int b = bi / HP, i = bi % HP;
    ushort* dst = xp + (size_t)bi * WP * CIN;
    const int tid = threadIdx.x;

    if (i == 0 || i == HP - 1) {
        i32x4 z = {0, 0, 0, 0};
        for (int k = tid; k < WP * CIN / 8; k += 256) ((i32x4*)dst)[k] = z;
        return;
    }

    __shared__ ushort t[W][CIN + 2];
    const int lane = tid & 63, wv = tid >> 6;
    if (lane < W) {
        const float* src = x + (size_t)b * CIN * HW + (size_t)(i - 1) * W + lane;
        for (int cin = wv; cin < CIN; cin += 4)
            t[lane][cin] = f2bf(src[(size_t)cin * HW]);
    }
    __syncthreads();
    for (int c = 0; c < WP; ++c)
        dst[c * CIN + tid] = (c == 0 || c == WP - 1) ? (ushort)0 : t[c - 1][tid];
}

// wb2: [t = cb*9+tap][cout][ci], ci = cin%32. Slab = 8192 elems.
__global__ __launch_bounds__(256)
void prep_wb2(const float* __restrict__ w, ushort* __restrict__ wb2) {
    const int d = blockIdx.x * 256 + threadIdx.x;
    const int ci = d & 31;
    const int cout = (d >> 5) & 255;
    const int r = d >> 13;                // 0..71
    const int tap = r % 9, cb = r / 9;
    const int cin = cb * 32 + ci;
    wb2[d] = f2bf(w[((size_t)cout * CIN + cin) * 9 + tap]);
}

// ---------------- MFMA conv ----------------

#define SCHED_FENCE() __builtin_amdgcn_sched_barrier(0)
#define WAITV(N) asm volatile("s_waitcnt vmcnt(" #N ")" ::: "memory")

__device__ __forceinline__ void gload_lds16(const ushort* g, ushort* l) {
    __builtin_amdgcn_global_load_lds(
        (const __attribute__((address_space(1))) void*)g,
        (__attribute__((address_space(3))) void*)l, 16, 0, 0);
}

// 16B-chunk involution: mixes bits 3-5 into 0-2; self-inverse; bits>=6 fixed.
__device__ __forceinline__ int swz(int c) { return c ^ ((c >> 3) & 7); }

__global__ __launch_bounds__(256, 3)
void conv_mfma(const ushort* __restrict__ xp, const ushort* __restrict__ wb2,
               float* __restrict__ out) {
    // XCD-aware swizzle: 1792 blocks = 8 * 224
    int bx = blockIdx.x;
    bx = (bx & 7) * 224 + (bx >> 3);

    const int mt = bx & 1;                 // cout tile: [128mt, 128mt+128)
    const int nt = bx >> 1;                // 896 = 32 b * 28 strips
    const int b  = nt / 28;
    const int p0 = (nt % 28) * 112;        // 112-pix strip = 2 output rows
    const int r0 = p0 / 56;                // first padded input row

    const int tid  = threadIdx.x;
    const int wv   = tid >> 6;             // 0..3, wave -> couts [32wv, 32wv+32) of tile
    const int lane = tid & 63;
    const int ml   = lane & 15;
    const int g    = lane >> 4;

    __shared__ ushort Xs[4 * 2048];        // 16KB: 4 row-regions x 256 chunks

    // B-frag chunk bases: pixel p_ = p0+16nf+ml -> region hl*256 + col*4 + g
    int cbase[7];
    #pragma unroll
    for (int nf = 0; nf < 7; ++nf) {
        const int p_  = p0 + 16 * nf + ml;
        const int hl  = (p_ >= p0 + 56) ? 1 : 0;
        const int col = p_ - 56 * (r0 + hl);
        cbase[nf] = hl * 256 + col * 4 + g;
    }
    // A-frag per-lane global elem offsets within a slab: frag mi = cout
    // (32wv+16mi+ml) of this tile, k-half g.
    int afo[2];
    #pragma unroll
    for (int mi = 0; mi < 2; ++mi)
        afo[mi] = (mt * 128 + 32 * wv + 16 * mi + ml) * 32 + 8 * g;
    // X row staging: position (rr*256+tid) holds chunk rr*256+ii (proven R13+)
    int xoff;
    {
        const int ii = (tid & 0xC0) | ((tid & 63) ^ (((tid & 63) >> 3) & 7));
        xoff = (ii < 232) ? ((ii >> 2) * CIN + (ii & 3) * 8) : 0;
    }
    const size_t xbase = ((size_t)b * HP + r0) * WP * CIN;

    f32x4 acc[2][7] = {};
    short8 aA[2][2], aB[2][2];             // parity reg-buffers (static idx only)

    #define STAGE_XPAIR(RR, CBN)                                                \
        { _Pragma("unroll")                                                     \
          for (int r_ = 0; r_ < 2; ++r_)                                        \
              gload_lds16(xp + xbase + (size_t)((RR) + r_) * WP * CIN           \
                              + (CBN) * 32 + xoff,                              \
                          &Xs[(((RR) + r_) * 256 + wv * 64) * 8]); }
    // load A frags for 2 taps starting at flat-tap T into BUF (4 loads)
    #define LOADA2(BUF, T)                                                      \
        { _Pragma("unroll")                                                     \
          for (int tp = 0; tp < 2; ++tp) {                                      \
              int _t = (T) + tp; if (_t >= 72) _t -= 72;                        \
              const ushort* _s = wb2 + (size_t)_t * 8192;                       \
              BUF[tp][0] = *(const short8*)(_s + afo[0]);                       \
              BUF[tp][1] = *(const short8*)(_s + afo[1]);                       \
          } }
    // load A frags for 1 tap (q4-target) into BUF slot 0 (2 loads)
    #define LOADA1(BUF, T)                                                      \
        { int _t = (T); if (_t >= 72) _t -= 72;                                 \
          const ushort* _s = wb2 + (size_t)_t * 8192;                           \
          BUF[0][0] = *(const short8*)(_s + afo[0]);                            \
          BUF[0][1] = *(const short8*)(_s + afo[1]); }

    // phase: wait -> barrier -> ds_read bv + MFMA (NTAPS taps from BUF) ->
    //        reload BUF with A(p+2) -> barrier. Tail X stages follow outside.
    #define PHASE(BUF, T0, NTAPS, HWAIT, LOADNEXT)                              \
        {                                                                       \
            WAITV(HWAIT);                                                       \
            SCHED_FENCE();                                                      \
            __builtin_amdgcn_s_barrier();                                       \
            SCHED_FENCE();                                                      \
            _Pragma("unroll")                                                   \
            for (int tp = 0; tp < (NTAPS); ++tp) {                              \
                const int tap = (T0) % 9 + tp;                                  \
                const int kh = tap / 3, kw = tap - kh * 3;                      \
                short8 bv[7];                                                   \
                _Pragma("unroll")                                               \
                for (int nf = 0; nf < 7; ++nf) {                                \
                    const int c = cbase[nf] + kh * 256 + kw * 4;                \
                    bv[nf] = *(const short8*)((const char*)Xs + swz(c) * 16);   \
                }                                                               \
                __builtin_amdgcn_s_setprio(1);                                  \
                _Pragma("unroll")                                               \
                for (int mi = 0; mi < 2; ++mi)                                  \
                    _Pragma("unroll")                                           \
                    for (int nf = 0; nf < 7; ++nf)                              \
                        acc[mi][nf] = __builtin_amdgcn_mfma_f32_16x16x32_bf16(  \
                                          BUF[tp][mi], bv[nf], acc[mi][nf],     \
                                          0, 0, 0);                             \
                __builtin_amdgcn_s_setprio(0);                                  \
            }                                                                   \
            LOADNEXT;                       /* anti-dep: after BUF's last use */\
            SCHED_FENCE();                                                      \
            __builtin_amdgcn_s_barrier();                                       \
            SCHED_FENCE();                                                      \
        }

    // prologue: X rows0-3(cb0) via gload_lds; A(q0)->aA, A(q1)->aB; drain; sync
    STAGE_XPAIR(0, 0);
    STAGE_XPAIR(2, 0);
    LOADA2(aA, 0);
    LOADA2(aB, 2);
    WAITV(0);
    __syncthreads();

    for (int cbp = 0; cbp < 4; ++cbp) {
        #pragma unroll
        for (int hf = 0; hf < 2; ++hf) {
            const int cb  = 2 * cbp + hf;
            const int t0  = 9 * cb;
            const int cbn = (cb < 7) ? cb + 1 : 0;  // cb7: dummy (dead/drained)
            // parity: cb even -> q0 uses aA; cb odd -> q0 uses aB (5 phases/cb)
            if (hf == 0) {
                PHASE(aA, t0 + 0, 2, 6, LOADA2(aA, t0 + 4));   // q0, loads q2
                PHASE(aB, t0 + 2, 2, 4, LOADA2(aB, t0 + 6));   // q1, loads q3
                PHASE(aA, t0 + 4, 2, 4, LOADA1(aA, t0 + 8));   // q2, loads q4
                STAGE_XPAIR(0, cbn);
                SCHED_FENCE();
                PHASE(aB, t0 + 6, 2, 4, LOADA2(aB, t0 + 9));   // q3, loads q0'
                PHASE(aA, t0 + 8, 1, 6, LOADA2(aA, t0 + 11));  // q4, loads q1'
                STAGE_XPAIR(2, cbn);
                SCHED_FENCE();
            } else {
                PHASE(aB, t0 + 0, 2, 6, LOADA2(aB, t0 + 4));
                PHASE(aA, t0 + 2, 2, 4, LOADA2(aA, t0 + 6));
                PHASE(aB, t0 + 4, 2, 4, LOADA1(aB, t0 + 8));
                STAGE_XPAIR(0, cbn);
                SCHED_FENCE();
                PHASE(aA, t0 + 6, 2, 4, LOADA2(aA, t0 + 9));
                PHASE(aB, t0 + 8, 1, 6, LOADA2(aB, t0 + 11));
                STAGE_XPAIR(2, cbn);
                SCHED_FENCE();
            }
        }
    }
    WAITV(0);                              // drain tail dummy stages

    // epilogue: D[row=4g+r][col=ml] (verified R2-R16)
    float* ob = out + (size_t)b * COUT * HW;
    #pragma unroll
    for (int mi = 0; mi < 2; ++mi)
        #pragma unroll
        for (int nf = 0; nf < 7; ++nf)
            #pragma unroll
            for (int r = 0; r < 4; ++r) {
                const int cout_l = mt * 128 + 32 * wv + 16 * mi + 4 * g + r;
                const int p_ = p0 + 16 * nf + ml;
                ob[(size_t)cout_l * HW + p_] = acc[mi][nf][r];
            }
    #undef STAGE_XPAIR
    #undef LOADA2
    #undef LOADA1
    #undef PHASE
}

// ---------------- R1 fallback (fp32 sparse direct) ----------------

constexpr int WSZ = CIN * 9;
constexpr int NIN = 54 * 54;

__global__ __launch_bounds__(256)
void sparse_conv3x3(const float* __restrict__ x,
                    const float* __restrict__ wgt,
                    float* __restrict__ out) {
    const int bc = blockIdx.x, cout = bc % COUT, b = bc / COUT;
    const int tid = threadIdx.x;
    __shared__ int2 s_ent[WSZ];
    __shared__ unsigned char s_kk[WSZ];
    __shared__ int s_cnt[257];
    const float* wc = wgt + (size_t)cout * WSZ;
    float mv[9]; int cnt = 0;
    #pragma unroll
    for (int i = 0; i < 9; ++i) { mv[i] = wc[tid * 9 + i]; if (mv[i] != 0.0f) cnt++; }
    s_cnt[tid] = cnt; __syncthreads();
    if (tid == 0) { int run = 0; for (int t = 0; t < 256; ++t) { int c = s_cnt[t]; s_cnt[t] = run; run += c; } s_cnt[256] = run; }
    __syncthreads();
    { int pos = s_cnt[tid];
      #pragma unroll
      for (int i = 0; i < 9; ++i) if (mv[i] != 0.0f) {
          const int kh = i / 3, kw = i - kh * 3;
          int2 e; e.x = (tid * HW + (kh - 1) * W + (kw - 1)) * 4; e.y = __float_as_int(mv[i]);
          s_ent[pos] = e; s_kk[pos] = (unsigned char)(kh | (kw << 4)); pos++; } }
    __syncthreads();
    const int nnz = s_cnt[256];
    const char* xb = (const char*)(x + (size_t)b * CIN * HW);
    float* ob = out + (size_t)bc * HW;
    for (int o = tid; o < HW; o += 256) {
        int h, w; bool interior = (o < NIN);
        if (interior) { h = 1 + o / 54; w = 1 + (o - (h - 1) * 54); }
        else { int o2 = o - NIN;
            if (o2 < 56) { h = 0; w = o2; } else if (o2 < 112) { h = 55; w = o2 - 56; }
            else if (o2 < 166) { h = 1 + (o2 - 112); w = 0; } else { h = 1 + (o2 - 166); w = 55; } }
        const char* pb = xb + (size_t)(h * W + w) * 4;
        float acc = 0.0f;
        if (interior) {
            #pragma unroll 4
            for (int e = 0; e < nnz; ++e) { const int2 en = s_ent[e];
                acc = fmaf(__int_as_float(en.y), *(const float*)(pb + en.x), acc); }
        } else {
            const int h1 = h - 1, w1 = w - 1;
            for (int e = 0; e < nnz; ++e) { const int2 en = s_ent[e]; const int kk = s_kk[e];
                const int hh = h1 + (kk & 15), ww = w1 + (kk >> 4);
                if ((unsigned)hh < (unsigned)H && (unsigned)ww < (unsigned)W)
                    acc = fmaf(__int_as_float(en.y), *(const float*)(pb + en.x), acc); } }
        ob[h * W + w] = acc;
    }
}

// ---------------- launch ----------------

extern "C" void kernel_launch(void* const* d_in, const int* in_sizes, int n_in,
                              void* d_out, int out_size, void* d_ws, size_t ws_size,
                              hipStream_t stream) {
    const float* x = (const float*)d_in[0];
    const float* w = (const float*)d_in[1];
    float* out = (float*)d_out;

    if (ws_size >= WS_NEEDED) {
        ushort* xp = (ushort*)d_ws;
        ushort* wbp = xp + XP_ELEMS;
        prep_xp<<<BB * HP, 256, 0, stream>>>(x, xp);
        prep_wb2<<<(int)(WB_ELEMS / 256), 256, 0, stream>>>(w, wbp);
        conv_mfma<<<1792, 256, 0, stream>>>(xp, wbp, out);
    } else {
        sparse_conv3x3<<<BB * COUT, 256, 0, stream>>>(x, w, out);
    }
}

// Round 18
// 205.213 us; speedup vs baseline: 1.2075x; 1.2075x over previous
//
#include <hip/hip_runtime.h>

// 3x3 conv (sparse weights treated dense), NCHW/OIHW, stride1 pad1, fp32 I/O.
// B=32, CIN=COUT=256, H=W=56.
//
// R18 = R17 (A in registers, X-only LDS) with SPILL-PROOF A buffers:
// 8 individually-NAMED short8 regs (aA00..aB11) passed explicitly through
// the macros — no arrays, no runtime indexing, nothing to demote to scratch.
// R17's counters (FETCH/WRITE both +~125MB, VGPR stuck at 84) showed the
// compiler spilled the aA/aB arrays to scratch rather than growing the
// allocation; the schedule itself refcheck'd and lifted occupancy to 28%.
//  - LDS: 16KB X rolling buffer only (R16 scheme). A: global->VGPR from
//    L2-resident wb2, 2-phase-ahead, loaded after the consumer phase's MFMAs.
//  - head waits {q0:6, q1:4, q2:4, q3:4, q4:6}; never 0 mid-loop.
//  - m2n7 wave, 128-cout blocks, grid 1792, swizzle/epilogue: R16/R17 verbatim.

typedef __attribute__((ext_vector_type(8))) short short8;
typedef __attribute__((ext_vector_type(4))) float f32x4;
typedef __attribute__((ext_vector_type(4))) int i32x4;

constexpr int BB = 32, CIN = 256, COUT = 256, H = 56, W = 56, HW = H * W;
constexpr int HP = 58, WP = 58;

constexpr size_t XP_ELEMS = (size_t)BB * HP * WP * CIN;
constexpr size_t WB_ELEMS = (size_t)COUT * 9 * CIN;
constexpr size_t WS_NEEDED = (XP_ELEMS + WB_ELEMS) * 2;

__device__ __forceinline__ ushort f2bf(float f) {
    unsigned x = __float_as_uint(f);
    unsigned r = (x + 0x7FFFu + ((x >> 16) & 1u)) >> 16;   // RNE
    return (ushort)r;
}

// ---------------- prep kernels (unchanged) ----------------

__global__ __launch_bounds__(256)
void prep_xp(const float* __restrict__ x, ushort* __restrict__ xp) {
    const int bi = blockIdx.x;            // b*58 + padded row i
    const int b = bi / HP, i = bi % HP;
    ushort* dst = xp + (size_t)bi * WP * CIN;
    const int tid = threadIdx.x;

    if (i == 0 || i == HP - 1) {
        i32x4 z = {0, 0, 0, 0};
        for (int k = tid; k < WP * CIN / 8; k += 256) ((i32x4*)dst)[k] = z;
        return;
    }

    __shared__ ushort t[W][CIN + 2];
    const int lane = tid & 63, wv = tid >> 6;
    if (lane < W) {
        const float* src = x + (size_t)b * CIN * HW + (size_t)(i - 1) * W + lane;
        for (int cin = wv; cin < CIN; cin += 4)
            t[lane][cin] = f2bf(src[(size_t)cin * HW]);
    }
    __syncthreads();
    for (int c = 0; c < WP; ++c)
        dst[c * CIN + tid] = (c == 0 || c == WP - 1) ? (ushort)0 : t[c - 1][tid];
}

// wb2: [t = cb*9+tap][cout][ci], ci = cin%32. Slab = 8192 elems.
__global__ __launch_bounds__(256)
void prep_wb2(const float* __restrict__ w, ushort* __restrict__ wb2) {
    const int d = blockIdx.x * 256 + threadIdx.x;
    const int ci = d & 31;
    const int cout = (d >> 5) & 255;
    const int r = d >> 13;                // 0..71
    const int tap = r % 9, cb = r / 9;
    const int cin = cb * 32 + ci;
    wb2[d] = f2bf(w[((size_t)cout * CIN + cin) * 9 + tap]);
}

// ---------------- MFMA conv ----------------

#define SCHED_FENCE() __builtin_amdgcn_sched_barrier(0)
#define WAITV(N) asm volatile("s_waitcnt vmcnt(" #N ")" ::: "memory")

__device__ __forceinline__ void gload_lds16(const ushort* g, ushort* l) {
    __builtin_amdgcn_global_load_lds(
        (const __attribute__((address_space(1))) void*)g,
        (__attribute__((address_space(3))) void*)l, 16, 0, 0);
}

// 16B-chunk involution: mixes bits 3-5 into 0-2; self-inverse; bits>=6 fixed.
__device__ __forceinline__ int swz(int c) { return c ^ ((c >> 3) & 7); }

__global__ __launch_bounds__(256, 3)
void conv_mfma(const ushort* __restrict__ xp, const ushort* __restrict__ wb2,
               float* __restrict__ out) {
    // XCD-aware swizzle: 1792 blocks = 8 * 224
    int bx = blockIdx.x;
    bx = (bx & 7) * 224 + (bx >> 3);

    const int mt = bx & 1;                 // cout tile: [128mt, 128mt+128)
    const int nt = bx >> 1;                // 896 = 32 b * 28 strips
    const int b  = nt / 28;
    const int p0 = (nt % 28) * 112;        // 112-pix strip = 2 output rows
    const int r0 = p0 / 56;                // first padded input row

    const int tid  = threadIdx.x;
    const int wv   = tid >> 6;             // 0..3, wave -> couts [32wv, 32wv+32) of tile
    const int lane = tid & 63;
    const int ml   = lane & 15;
    const int g    = lane >> 4;

    __shared__ ushort Xs[4 * 2048];        // 16KB: 4 row-regions x 256 chunks

    // B-frag chunk bases: pixel p_ = p0+16nf+ml -> region hl*256 + col*4 + g
    int cbase[7];
    #pragma unroll
    for (int nf = 0; nf < 7; ++nf) {
        const int p_  = p0 + 16 * nf + ml;
        const int hl  = (p_ >= p0 + 56) ? 1 : 0;
        const int col = p_ - 56 * (r0 + hl);
        cbase[nf] = hl * 256 + col * 4 + g;
    }
    // A-frag per-lane global elem offsets within a slab (scalars, not arrays)
    const int afo0 = (mt * 128 + 32 * wv + ml) * 32 + 8 * g;
    const int afo1 = (mt * 128 + 32 * wv + 16 + ml) * 32 + 8 * g;
    // X row staging: position (rr*256+tid) holds chunk rr*256+ii (proven R13+)
    int xoff;
    {
        const int ii = (tid & 0xC0) | ((tid & 63) ^ (((tid & 63) >> 3) & 7));
        xoff = (ii < 232) ? ((ii >> 2) * CIN + (ii & 3) * 8) : 0;
    }
    const size_t xbase = ((size_t)b * HP + r0) * WP * CIN;

    f32x4 acc[2][7] = {};
    // named A registers — nothing for the allocator to demote
    short8 aA00, aA01, aA10, aA11;
    short8 aB00, aB01, aB10, aB11;

    #define STAGE_XPAIR(RR, CBN)                                                \
        { _Pragma("unroll")                                                     \
          for (int r_ = 0; r_ < 2; ++r_)                                        \
              gload_lds16(xp + xbase + (size_t)((RR) + r_) * WP * CIN           \
                              + (CBN) * 32 + xoff,                              \
                          &Xs[(((RR) + r_) * 256 + wv * 64) * 8]); }
    #define LOADA2(V00, V01, V10, V11, T)                                       \
        { int _t0 = (T);     if (_t0 >= 72) _t0 -= 72;                          \
          int _t1 = (T) + 1; if (_t1 >= 72) _t1 -= 72;                          \
          const ushort* _s0 = wb2 + (size_t)_t0 * 8192;                         \
          const ushort* _s1 = wb2 + (size_t)_t1 * 8192;                         \
          V00 = *(const short8*)(_s0 + afo0);                                   \
          V01 = *(const short8*)(_s0 + afo1);                                   \
          V10 = *(const short8*)(_s1 + afo0);                                   \
          V11 = *(const short8*)(_s1 + afo1); }
    #define LOADA1(V00, V01, T)                                                 \
        { int _t0 = (T); if (_t0 >= 72) _t0 -= 72;                              \
          const ushort* _s0 = wb2 + (size_t)_t0 * 8192;                         \
          V00 = *(const short8*)(_s0 + afo0);                                   \
          V01 = *(const short8*)(_s0 + afo1); }

    // one tap's ds_read + 14 MFMA using two named A frags
    #define TAPBODY(TAP, V0, V1)                                                \
        {                                                                       \
            const int kh = (TAP) / 3, kw = (TAP) - kh * 3;                      \
            short8 bv[7];                                                       \
            _Pragma("unroll")                                                   \
            for (int nf = 0; nf < 7; ++nf) {                                    \
                const int c = cbase[nf] + kh * 256 + kw * 4;                    \
                bv[nf] = *(const short8*)((const char*)Xs + swz(c) * 16);       \
            }                                                                   \
            __builtin_amdgcn_s_setprio(1);                                      \
            _Pragma("unroll")                                                   \
            for (int nf = 0; nf < 7; ++nf) {                                    \
                acc[0][nf] = __builtin_amdgcn_mfma_f32_16x16x32_bf16(           \
                                 V0, bv[nf], acc[0][nf], 0, 0, 0);              \
                acc[1][nf] = __builtin_amdgcn_mfma_f32_16x16x32_bf16(           \
                                 V1, bv[nf], acc[1][nf], 0, 0, 0);              \
            }                                                                   \
            __builtin_amdgcn_s_setprio(0);                                      \
        }

    #define PHASE2(VA0, VA1, VB0, VB1, TAP0, HWAIT, LOADNEXT)                   \
        {                                                                       \
            WAITV(HWAIT);                                                       \
            SCHED_FENCE();                                                      \
            __builtin_amdgcn_s_barrier();                                       \
            SCHED_FENCE();                                                      \
            TAPBODY((TAP0),     VA0, VA1);                                      \
            TAPBODY((TAP0) + 1, VB0, VB1);                                      \
            LOADNEXT;                      /* anti-dep: after last use */       \
            SCHED_FENCE();                                                      \
            __builtin_amdgcn_s_barrier();                                       \
            SCHED_FENCE();                                                      \
        }
    #define PHASE1(VA0, VA1, TAP0, HWAIT, LOADNEXT)                             \
        {                                                                       \
            WAITV(HWAIT);                                                       \
            SCHED_FENCE();                                                      \
            __builtin_amdgcn_s_barrier();                                       \
            SCHED_FENCE();                                                      \
            TAPBODY((TAP0), VA0, VA1);                                          \
            LOADNEXT;                                                           \
            SCHED_FENCE();                                                      \
            __builtin_amdgcn_s_barrier();                                       \
            SCHED_FENCE();                                                      \
        }

    // prologue: X rows0-3(cb0); A(taps 0-1)->aA, A(taps 2-3)->aB; drain; sync
    STAGE_XPAIR(0, 0);
    STAGE_XPAIR(2, 0);
    LOADA2(aA00, aA01, aA10, aA11, 0);
    LOADA2(aB00, aB01, aB10, aB11, 2);
    WAITV(0);
    __syncthreads();

    for (int cbp = 0; cbp < 4; ++cbp) {
        #pragma unroll
        for (int hf = 0; hf < 2; ++hf) {
            const int cb  = 2 * cbp + hf;
            const int t0  = 9 * cb;
            const int cbn = (cb < 7) ? cb + 1 : 0;  // cb7: dummy (dead/drained)
            if (hf == 0) {
                PHASE2(aA00, aA01, aA10, aA11, 0, 6,
                       LOADA2(aA00, aA01, aA10, aA11, t0 + 4));   // q0, loads q2
                PHASE2(aB00, aB01, aB10, aB11, 2, 4,
                       LOADA2(aB00, aB01, aB10, aB11, t0 + 6));   // q1, loads q3
                PHASE2(aA00, aA01, aA10, aA11, 4, 4,
                       LOADA1(aA00, aA01, t0 + 8));               // q2, loads q4
                STAGE_XPAIR(0, cbn);
                SCHED_FENCE();
                PHASE2(aB00, aB01, aB10, aB11, 6, 4,
                       LOADA2(aB00, aB01, aB10, aB11, t0 + 9));   // q3, loads q0'
                PHASE1(aA00, aA01, 8, 6,
                       LOADA2(aA00, aA01, aA10, aA11, t0 + 11));  // q4, loads q1'
                STAGE_XPAIR(2, cbn);
                SCHED_FENCE();
            } else {
                PHASE2(aB00, aB01, aB10, aB11, 0, 6,
                       LOADA2(aB00, aB01, aB10, aB11, t0 + 4));
                PHASE2(aA00, aA01, aA10, aA11, 2, 4,
                       LOADA2(aA00, aA01, aA10, aA11, t0 + 6));
                PHASE2(aB00, aB01, aB10, aB11, 4, 4,
                       LOADA1(aB00, aB01, t0 + 8));
                STAGE_XPAIR(0, cbn);
                SCHED_FENCE();
                PHASE2(aA00, aA01, aA10, aA11, 6, 4,
                       LOADA2(aA00, aA01, aA10, aA11, t0 + 9));
                PHASE1(aB00, aB01, 8, 6,
                       LOADA2(aB00, aB01, aB10, aB11, t0 + 11));
                STAGE_XPAIR(2, cbn);
                SCHED_FENCE();
            }
        }
    }
    WAITV(0);                              // drain tail dummy stages

    // epilogue: D[row=4g+r][col=ml] (verified R2-R17)
    float* ob = out + (size_t)b * COUT * HW;
    #pragma unroll
    for (int mi = 0; mi < 2; ++mi)
        #pragma unroll
        for (int nf = 0; nf < 7; ++nf)
            #pragma unroll
            for (int r = 0; r < 4; ++r) {
                const int cout_l = mt * 128 + 32 * wv + 16 * mi + 4 * g + r;
                const int p_ = p0 + 16 * nf + ml;
                ob[(size_t)cout_l * HW + p_] = acc[mi][nf][r];
            }
    #undef STAGE_XPAIR
    #undef LOADA2
    #undef LOADA1
    #undef TAPBODY
    #undef PHASE2
    #undef PHASE1
}

// ---------------- R1 fallback (fp32 sparse direct) ----------------

constexpr int WSZ = CIN * 9;
constexpr int NIN = 54 * 54;

__global__ __launch_bounds__(256)
void sparse_conv3x3(const float* __restrict__ x,
                    const float* __restrict__ wgt,
                    float* __restrict__ out) {
    const int bc = blockIdx.x, cout = bc % COUT, b = bc / COUT;
    const int tid = threadIdx.x;
    __shared__ int2 s_ent[WSZ];
    __shared__ unsigned char s_kk[WSZ];
    __shared__ int s_cnt[257];
    const float* wc = wgt + (size_t)cout * WSZ;
    float mv[9]; int cnt = 0;
    #pragma unroll
    for (int i = 0; i < 9; ++i) { mv[i] = wc[tid * 9 + i]; if (mv[i] != 0.0f) cnt++; }
    s_cnt[tid] = cnt; __syncthreads();
    if (tid == 0) { int run = 0; for (int t = 0; t < 256; ++t) { int c = s_cnt[t]; s_cnt[t] = run; run += c; } s_cnt[256] = run; }
    __syncthreads();
    { int pos = s_cnt[tid];
      #pragma unroll
      for (int i = 0; i < 9; ++i) if (mv[i] != 0.0f) {
          const int kh = i / 3, kw = i - kh * 3;
          int2 e; e.x = (tid * HW + (kh - 1) * W + (kw - 1)) * 4; e.y = __float_as_int(mv[i]);
          s_ent[pos] = e; s_kk[pos] = (unsigned char)(kh | (kw << 4)); pos++; } }
    __syncthreads();
    const int nnz = s_cnt[256];
    const char* xb = (const char*)(x + (size_t)b * CIN * HW);
    float* ob = out + (size_t)bc * HW;
    for (int o = tid; o < HW; o += 256) {
        int h, w; bool interior = (o < NIN);
        if (interior) { h = 1 + o / 54; w = 1 + (o - (h - 1) * 54); }
        else { int o2 = o - NIN;
            if (o2 < 56) { h = 0; w = o2; } else if (o2 < 112) { h = 55; w = o2 - 56; }
            else if (o2 < 166) { h = 1 + (o2 - 112); w = 0; } else { h = 1 + (o2 - 166); w = 55; } }
        const char* pb = xb + (size_t)(h * W + w) * 4;
        float acc = 0.0f;
        if (interior) {
            #pragma unroll 4
            for (int e = 0; e < nnz; ++e) { const int2 en = s_ent[e];
                acc = fmaf(__int_as_float(en.y), *(const float*)(pb + en.x), acc); }
        } else {
            const int h1 = h - 1, w1 = w - 1;
            for (int e = 0; e < nnz; ++e) { const int2 en = s_ent[e]; const int kk = s_kk[e];
                const int hh = h1 + (kk & 15), ww = w1 + (kk >> 4);
                if ((unsigned)hh < (unsigned)H && (unsigned)ww < (unsigned)W)
                    acc = fmaf(__int_as_float(en.y), *(const float*)(pb + en.x), acc); } }
        ob[h * W + w] = acc;
    }
}

// ---------------- launch ----------------

extern "C" void kernel_launch(void* const* d_in, const int* in_sizes, int n_in,
                              void* d_out, int out_size, void* d_ws, size_t ws_size,
                              hipStream_t stream) {
    const float* x = (const float*)d_in[0];
    const float* w = (const float*)d_in[1];
    float* out = (float*)d_out;

    if (ws_size >= WS_NEEDED) {
        ushort* xp = (ushort*)d_ws;
        ushort* wbp = xp + XP_ELEMS;
        prep_xp<<<BB * HP, 256, 0, stream>>>(x, xp);
        prep_wb2<<<(int)(WB_ELEMS / 256), 256, 0, stream>>>(w, wbp);
        conv_mfma<<<1792, 256, 0, stream>>>(xp, wbp, out);
    } else {
        sparse_conv3x3<<<BB * COUT, 256, 0, stream>>>(x, w, out);
    }
}

// Round 20
// 163.679 us; speedup vs baseline: 1.5139x; 1.2537x over previous
//
#include <hip/hip_runtime.h>

// 3x3 conv (sparse weights treated dense), NCHW/OIHW, stride1 pad1, fp32 I/O.
// B=32, CIN=COUT=256, H=W=56.
//
// R20 = R19 (A in a single 16-VGPR named reg buffer, X-only 16KB LDS) with
// the X stages moved back to R16's PROVEN placement: AFTER the post-MFMA
// barrier, BEFORE the next head barrier. R19's failure was a WAR race: the
// in-phase q2-tail stage wrote LDS row 1 while other waves still read it
// (gload_lds writes are ordered only by vmcnt, not by intra-phase program
// order). Stage-after-barrier is what made R13/R15/R16 safe.
//  - Register ledger: (256,3) cap ~168; 84 arch + 56 AGPR + 16 A-regs = 156.
//  - FIFO waits (post-barrier stages): q0 vmcnt(8) retires X01 (oldest-first
//    makes this robust to compiler-inserted A waits); q1 vmcnt(4) retires
//    X23 before tap3 reads row 2. A-reg deps: compiler auto-waits.
//  - m2n7 wave, 128-cout blocks, grid 1792, swizzle/epilogue: R16 verbatim.

typedef __attribute__((ext_vector_type(8))) short short8;
typedef __attribute__((ext_vector_type(4))) float f32x4;
typedef __attribute__((ext_vector_type(4))) int i32x4;

constexpr int BB = 32, CIN = 256, COUT = 256, H = 56, W = 56, HW = H * W;
constexpr int HP = 58, WP = 58;

constexpr size_t XP_ELEMS = (size_t)BB * HP * WP * CIN;
constexpr size_t WB_ELEMS = (size_t)COUT * 9 * CIN;
constexpr size_t WS_NEEDED = (XP_ELEMS + WB_ELEMS) * 2;

__device__ __forceinline__ ushort f2bf(float f) {
    unsigned x = __float_as_uint(f);
    unsigned r = (x + 0x7FFFu + ((x >> 16) & 1u)) >> 16;   // RNE
    return (ushort)r;
}

// ---------------- prep kernels (unchanged) ----------------

__global__ __launch_bounds__(256)
void prep_xp(const float* __restrict__ x, ushort* __restrict__ xp) {
    const int bi = blockIdx.x;            // b*58 + padded row i
    const int b = bi / HP, i = bi % HP;
    ushort* dst = xp + (size_t)bi * WP * CIN;
    const int tid = threadIdx.x;

    if (i == 0 || i == HP - 1) {
        i32x4 z = {0, 0, 0, 0};
        for (int k = tid; k < WP * CIN / 8; k += 256) ((i32x4*)dst)[k] = z;
        return;
    }

    __shared__ ushort t[W][CIN + 2];
    const int lane = tid & 63, wv = tid >> 6;
    if (lane < W) {
        const float* src = x + (size_t)b * CIN * HW + (size_t)(i - 1) * W + lane;
        for (int cin = wv; cin < CIN; cin += 4)
            t[lane][cin] = f2bf(src[(size_t)cin * HW]);
    }
    __syncthreads();
    for (int c = 0; c < WP; ++c)
        dst[c * CIN + tid] = (c == 0 || c == WP - 1) ? (ushort)0 : t[c - 1][tid];
}

// wb2: [t = cb*9+tap][cout][ci], ci = cin%32. Slab = 8192 elems.
__global__ __launch_bounds__(256)
void prep_wb2(const float* __restrict__ w, ushort* __restrict__ wb2) {
    const int d = blockIdx.x * 256 + threadIdx.x;
    const int ci = d & 31;
    const int cout = (d >> 5) & 255;
    const int r = d >> 13;                // 0..71
    const int tap = r % 9, cb = r / 9;
    const int cin = cb * 32 + ci;
    wb2[d] = f2bf(w[((size_t)cout * CIN + cin) * 9 + tap]);
}

// ---------------- MFMA conv ----------------

#define SCHED_FENCE() __builtin_amdgcn_sched_barrier(0)
#define WAITV(N) asm volatile("s_waitcnt vmcnt(" #N ")" ::: "memory")

__device__ __forceinline__ void gload_lds16(const ushort* g, ushort* l) {
    __builtin_amdgcn_global_load_lds(
        (const __attribute__((address_space(1))) void*)g,
        (__attribute__((address_space(3))) void*)l, 16, 0, 0);
}

// 16B-chunk involution: mixes bits 3-5 into 0-2; self-inverse; bits>=6 fixed.
__device__ __forceinline__ int swz(int c) { return c ^ ((c >> 3) & 7); }

__global__ __launch_bounds__(256, 3)
void conv_mfma(const ushort* __restrict__ xp, const ushort* __restrict__ wb2,
               float* __restrict__ out) {
    // XCD-aware swizzle: 1792 blocks = 8 * 224
    int bx = blockIdx.x;
    bx = (bx & 7) * 224 + (bx >> 3);

    const int mt = bx & 1;                 // cout tile: [128mt, 128mt+128)
    const int nt = bx >> 1;                // 896 = 32 b * 28 strips
    const int b  = nt / 28;
    const int p0 = (nt % 28) * 112;        // 112-pix strip = 2 output rows
    const int r0 = p0 / 56;                // first padded input row

    const int tid  = threadIdx.x;
    const int wv   = tid >> 6;             // 0..3, wave -> couts [32wv, 32wv+32) of tile
    const int lane = tid & 63;
    const int ml   = lane & 15;
    const int g    = lane >> 4;

    __shared__ ushort Xs[4 * 2048];        // 16KB: 4 row-regions x 256 chunks

    // B-frag chunk bases: pixel p_ = p0+16nf+ml -> region hl*256 + col*4 + g
    int cbase[7];
    #pragma unroll
    for (int nf = 0; nf < 7; ++nf) {
        const int p_  = p0 + 16 * nf + ml;
        const int hl  = (p_ >= p0 + 56) ? 1 : 0;
        const int col = p_ - 56 * (r0 + hl);
        cbase[nf] = hl * 256 + col * 4 + g;
    }
    // A-frag per-lane global elem offsets within a slab (scalars)
    const int afo0 = (mt * 128 + 32 * wv + ml) * 32 + 8 * g;
    const int afo1 = (mt * 128 + 32 * wv + 16 + ml) * 32 + 8 * g;
    // X row staging: position (rr*256+tid) holds chunk rr*256+ii (proven R13+)
    int xoff;
    {
        const int ii = (tid & 0xC0) | ((tid & 63) ^ (((tid & 63) >> 3) & 7));
        xoff = (ii < 232) ? ((ii >> 2) * CIN + (ii & 3) * 8) : 0;
    }
    const size_t xbase = ((size_t)b * HP + r0) * WP * CIN;

    f32x4 acc[2][7] = {};
    // single named A buffer: 2 taps x 2 frags = 16 VGPR
    short8 aA00, aA01, aA10, aA11;

    #define STAGE_XPAIR(RR, CBN)                                                \
        { _Pragma("unroll")                                                     \
          for (int r_ = 0; r_ < 2; ++r_)                                        \
              gload_lds16(xp + xbase + (size_t)((RR) + r_) * WP * CIN           \
                              + (CBN) * 32 + xoff,                              \
                          &Xs[(((RR) + r_) * 256 + wv * 64) * 8]); }
    // load A frags for 2 consecutive taps (flat tap T, wraps at 72)
    #define LOADA2(T)                                                           \
        { int _t0 = (T);     if (_t0 >= 72) _t0 -= 72;                          \
          int _t1 = (T) + 1; if (_t1 >= 72) _t1 -= 72;                          \
          const ushort* _s0 = wb2 + (size_t)_t0 * 8192;                         \
          const ushort* _s1 = wb2 + (size_t)_t1 * 8192;                         \
          aA00 = *(const short8*)(_s0 + afo0);                                  \
          aA01 = *(const short8*)(_s0 + afo1);                                  \
          aA10 = *(const short8*)(_s1 + afo0);                                  \
          aA11 = *(const short8*)(_s1 + afo1); }
    #define LOADA1(T)                                                           \
        { int _t0 = (T); if (_t0 >= 72) _t0 -= 72;                              \
          const ushort* _s0 = wb2 + (size_t)_t0 * 8192;                         \
          aA00 = *(const short8*)(_s0 + afo0);                                  \
          aA01 = *(const short8*)(_s0 + afo1); }

    // one tap's ds_read + 14 MFMA using two named A frags (TAP is 0..8 literal)
    #define TAPBODY(TAP, V0, V1)                                                \
        {                                                                       \
            const int kh = (TAP) / 3, kw = (TAP) - kh * 3;                      \
            short8 bv[7];                                                       \
            _Pragma("unroll")                                                   \
            for (int nf = 0; nf < 7; ++nf) {                                    \
                const int c = cbase[nf] + kh * 256 + kw * 4;                    \
                bv[nf] = *(const short8*)((const char*)Xs + swz(c) * 16);       \
            }                                                                   \
            __builtin_amdgcn_s_setprio(1);                                      \
            _Pragma("unroll")                                                   \
            for (int nf = 0; nf < 7; ++nf) {                                    \
                acc[0][nf] = __builtin_amdgcn_mfma_f32_16x16x32_bf16(           \
                                 V0, bv[nf], acc[0][nf], 0, 0, 0);              \
                acc[1][nf] = __builtin_amdgcn_mfma_f32_16x16x32_bf16(           \
                                 V1, bv[nf], acc[1][nf], 0, 0, 0);              \
            }                                                                   \
            __builtin_amdgcn_s_setprio(0);                                      \
        }

    // prologue: X rows0-3(cb0); A(taps 0,1); drain; sync
    STAGE_XPAIR(0, 0);
    STAGE_XPAIR(2, 0);
    LOADA2(0);
    WAITV(0);
    __syncthreads();

    for (int cb = 0; cb < 8; ++cb) {
        const int t0  = 9 * cb;
        const int cbn = (cb < 7) ? cb + 1 : 0;   // cb7: dummy (dead/drained)

        // ---- q0: taps 0,1 (rows 0-1). X01(this cb) must have landed. ----
        WAITV(8);  SCHED_FENCE();
        __builtin_amdgcn_s_barrier();  SCHED_FENCE();
        TAPBODY(0, aA00, aA01);
        TAPBODY(1, aA10, aA11);
        LOADA2(t0 + 2);
        SCHED_FENCE();
        __builtin_amdgcn_s_barrier();  SCHED_FENCE();

        // ---- q1: taps 2,3 (rows 0-2). X23(this cb) must have landed. ----
        WAITV(4);  SCHED_FENCE();
        __builtin_amdgcn_s_barrier();  SCHED_FENCE();
        TAPBODY(2, aA00, aA01);
        TAPBODY(3, aA10, aA11);
        LOADA2(t0 + 4);
        SCHED_FENCE();
        __builtin_amdgcn_s_barrier();  SCHED_FENCE();

        // ---- q2: taps 4,5 (rows 1-2) ----
        __builtin_amdgcn_s_barrier();  SCHED_FENCE();
        TAPBODY(4, aA00, aA01);
        TAPBODY(5, aA10, aA11);
        LOADA2(t0 + 6);
        SCHED_FENCE();
        __builtin_amdgcn_s_barrier();  SCHED_FENCE();
        // stage AFTER the barrier (R16 placement): all waves done reading row 1
        STAGE_XPAIR(0, cbn);
        SCHED_FENCE();

        // ---- q3: taps 6,7 (rows 2-3) ----
        __builtin_amdgcn_s_barrier();  SCHED_FENCE();
        TAPBODY(6, aA00, aA01);
        TAPBODY(7, aA10, aA11);
        LOADA1(t0 + 8);
        SCHED_FENCE();
        __builtin_amdgcn_s_barrier();  SCHED_FENCE();

        // ---- q4: tap 8 (rows 2-3) ----
        __builtin_amdgcn_s_barrier();  SCHED_FENCE();
        TAPBODY(8, aA00, aA01);
        LOADA2(t0 + 9);
        SCHED_FENCE();
        __builtin_amdgcn_s_barrier();  SCHED_FENCE();
        // stage AFTER the barrier: all waves done reading rows 2-3
        STAGE_XPAIR(2, cbn);
        SCHED_FENCE();
    }
    WAITV(0);                              // drain tail dummy stages

    // epilogue: D[row=4g+r][col=ml] (verified R2-R18)
    float* ob = out + (size_t)b * COUT * HW;
    #pragma unroll
    for (int mi = 0; mi < 2; ++mi)
        #pragma unroll
        for (int nf = 0; nf < 7; ++nf)
            #pragma unroll
            for (int r = 0; r < 4; ++r) {
                const int cout_l = mt * 128 + 32 * wv + 16 * mi + 4 * g + r;
                const int p_ = p0 + 16 * nf + ml;
                ob[(size_t)cout_l * HW + p_] = acc[mi][nf][r];
            }
    #undef STAGE_XPAIR
    #undef LOADA2
    #undef LOADA1
    #undef TAPBODY
}

// ---------------- R1 fallback (fp32 sparse direct) ----------------

constexpr int WSZ = CIN * 9;
constexpr int NIN = 54 * 54;

__global__ __launch_bounds__(256)
void sparse_conv3x3(const float* __restrict__ x,
                    const float* __restrict__ wgt,
                    float* __restrict__ out) {
    const int bc = blockIdx.x, cout = bc % COUT, b = bc / COUT;
    const int tid = threadIdx.x;
    __shared__ int2 s_ent[WSZ];
    __shared__ unsigned char s_kk[WSZ];
    __shared__ int s_cnt[257];
    const float* wc = wgt + (size_t)cout * WSZ;
    float mv[9]; int cnt = 0;
    #pragma unroll
    for (int i = 0; i < 9; ++i) { mv[i] = wc[tid * 9 + i]; if (mv[i] != 0.0f) cnt++; }
    s_cnt[tid] = cnt; __syncthreads();
    if (tid == 0) { int run = 0; for (int t = 0; t < 256; ++t) { int c = s_cnt[t]; s_cnt[t] = run; run += c; } s_cnt[256] = run; }
    __syncthreads();
    { int pos = s_cnt[tid];
      #pragma unroll
      for (int i = 0; i < 9; ++i) if (mv[i] != 0.0f) {
          const int kh = i / 3, kw = i - kh * 3;
          int2 e; e.x = (tid * HW + (kh - 1) * W + (kw - 1)) * 4; e.y = __float_as_int(mv[i]);
          s_ent[pos] = e; s_kk[pos] = (unsigned char)(kh | (kw << 4)); pos++; } }
    __syncthreads();
    const int nnz = s_cnt[256];
    const char* xb = (const char*)(x + (size_t)b * CIN * HW);
    float* ob = out + (size_t)bc * HW;
    for (int o = tid; o < HW; o += 256) {
        int h, w; bool interior = (o < NIN);
        if (interior) { h = 1 + o / 54; w = 1 + (o - (h - 1) * 54); }
        else { int o2 = o - NIN;
            if (o2 < 56) { h = 0; w = o2; } else if (o2 < 112) { h = 55; w = o2 - 56; }
            else if (o2 < 166) { h = 1 + (o2 - 112); w = 0; } else { h = 1 + (o2 - 166); w = 55; } }
        const char* pb = xb + (size_t)(h * W + w) * 4;
        float acc = 0.0f;
        if (interior) {
            #pragma unroll 4
            for (int e = 0; e < nnz; ++e) { const int2 en = s_ent[e];
                acc = fmaf(__int_as_float(en.y), *(const float*)(pb + en.x), acc); }
        } else {
            const int h1 = h - 1, w1 = w - 1;
            for (int e = 0; e < nnz; ++e) { const int2 en = s_ent[e]; const int kk = s_kk[e];
                const int hh = h1 + (kk & 15), ww = w1 + (kk >> 4);
                if ((unsigned)hh < (unsigned)H && (unsigned)ww < (unsigned)W)
                    acc = fmaf(__int_as_float(en.y), *(const float*)(pb + en.x), acc); } }
        ob[h * W + w] = acc;
    }
}

// ---------------- launch ----------------

extern "C" void kernel_launch(void* const* d_in, const int* in_sizes, int n_in,
                              void* d_out, int out_size, void* d_ws, size_t ws_size,
                              hipStream_t stream) {
    const float* x = (const float*)d_in[0];
    const float* w = (const float*)d_in[1];
    float* out = (float*)d_out;

    if (ws_size >= WS_NEEDED) {
        ushort* xp = (ushort*)d_ws;
        ushort* wbp = xp + XP_ELEMS;
        prep_xp<<<BB * HP, 256, 0, stream>>>(x, xp);
        prep_wb2<<<(int)(WB_ELEMS / 256), 256, 0, stream>>>(w, wbp);
        conv_mfma<<<1792, 256, 0, stream>>>(xp, wbp, out);
    } else {
        sparse_conv3x3<<<BB * COUT, 256, 0, stream>>>(x, w, out);
    }
}

// Round 21
// 143.560 us; speedup vs baseline: 1.7261x; 1.1401x over previous
//
#include <hip/hip_runtime.h>

// 3x3 conv (sparse weights treated dense), NCHW/OIHW, stride1 pad1, fp32 I/O.
// B=32, CIN=COUT=256, H=W=56.
//
// R21 = R16 verbatim (the session's best verified kernel: conv 116.2us,
// total 143.7us, MfmaUtil 43%, 3 blocks/CU, no spill).
// A-in-regs (R17-R20) concluded negative: the allocator pins arch VGPRs at
// 84 under this barrier structure and spills the A buffers; 1-phase-ahead
// cover < L2 latency. R16's all-gload_lds 2-tap-phase pipeline stands.
//  - block 128 cout x 112 pix, 4 waves of 32c x 112p (m2n7, acc[2][7]=56 AGPR)
//  - A slab 8KB via gload_lds, 2 parity bufs x 2 slabs; X single 16KB rolling
//    region buffer (rows01 @ q2-tail, rows23 @ q4-tail, after the barrier)
//  - FIFO head waits {q0:6, q1:4, q2:4, q3:4, q4:4}; never 0 mid-loop
//  - swz(c)=c^((c>>3)&7) both-sides LDS swizzle; XCD-aware grid 1792=8*224

typedef __attribute__((ext_vector_type(8))) short short8;
typedef __attribute__((ext_vector_type(4))) float f32x4;
typedef __attribute__((ext_vector_type(4))) int i32x4;

constexpr int BB = 32, CIN = 256, COUT = 256, H = 56, W = 56, HW = H * W;
constexpr int HP = 58, WP = 58;

constexpr size_t XP_ELEMS = (size_t)BB * HP * WP * CIN;
constexpr size_t WB_ELEMS = (size_t)COUT * 9 * CIN;
constexpr size_t WS_NEEDED = (XP_ELEMS + WB_ELEMS) * 2;

__device__ __forceinline__ ushort f2bf(float f) {
    unsigned x = __float_as_uint(f);
    unsigned r = (x + 0x7FFFu + ((x >> 16) & 1u)) >> 16;   // RNE
    return (ushort)r;
}

// ---------------- prep kernels ----------------

__global__ __launch_bounds__(256)
void prep_xp(const float* __restrict__ x, ushort* __restrict__ xp) {
    const int bi = blockIdx.x;            // b*58 + padded row i
    const int b = bi / HP, i = bi % HP;
    ushort* dst = xp + (size_t)bi * WP * CIN;
    const int tid = threadIdx.x;

    if (i == 0 || i == HP - 1) {
        i32x4 z = {0, 0, 0, 0};
        for (int k = tid; k < WP * CIN / 8; k += 256) ((i32x4*)dst)[k] = z;
        return;
    }

    __shared__ ushort t[W][CIN + 2];
    const int lane = tid & 63, wv = tid >> 6;
    if (lane < W) {
        const float* src = x + (size_t)b * CIN * HW + (size_t)(i - 1) * W + lane;
        for (int cin = wv; cin < CIN; cin += 4)
            t[lane][cin] = f2bf(src[(size_t)cin * HW]);
    }
    __syncthreads();
    for (int c = 0; c < WP; ++c)
        dst[c * CIN + tid] = (c == 0 || c == WP - 1) ? (ushort)0 : t[c - 1][tid];
}

// wb2: [t = cb*9+tap][cout][ci], ci = cin%32. Slab = 8192 elems (256 couts).
__global__ __launch_bounds__(256)
void prep_wb2(const float* __restrict__ w, ushort* __restrict__ wb2) {
    const int d = blockIdx.x * 256 + threadIdx.x;
    const int ci = d & 31;
    const int cout = (d >> 5) & 255;
    const int r = d >> 13;                // 0..71
    const int tap = r % 9, cb = r / 9;
    const int cin = cb * 32 + ci;
    wb2[d] = f2bf(w[((size_t)cout * CIN + cin) * 9 + tap]);
}

// ---------------- MFMA conv ----------------

#define SCHED_FENCE() __builtin_amdgcn_sched_barrier(0)
#define WAITV(N) asm volatile("s_waitcnt vmcnt(" #N ")" ::: "memory")

__device__ __forceinline__ void gload_lds16(const ushort* g, ushort* l) {
    __builtin_amdgcn_global_load_lds(
        (const __attribute__((address_space(1))) void*)g,
        (__attribute__((address_space(3))) void*)l, 16, 0, 0);
}

// 16B-chunk involution: mixes bits 3-5 into 0-2; self-inverse; bits>=6 fixed.
__device__ __forceinline__ int swz(int c) { return c ^ ((c >> 3) & 7); }

__global__ __launch_bounds__(256, 3)
void conv_mfma(const ushort* __restrict__ xp, const ushort* __restrict__ wb2,
               float* __restrict__ out) {
    // XCD-aware swizzle: 1792 blocks = 8 * 224
    int bx = blockIdx.x;
    bx = (bx & 7) * 224 + (bx >> 3);

    const int mt = bx & 1;                 // cout tile: [128mt, 128mt+128)
    const int nt = bx >> 1;                // 896 = 32 b * 28 strips
    const int b  = nt / 28;
    const int p0 = (nt % 28) * 112;        // 112-pix strip = 2 output rows
    const int r0 = p0 / 56;                // first padded input row

    const int tid  = threadIdx.x;
    const int wv   = tid >> 6;             // 0..3, wave -> couts [32wv, 32wv+32) of tile
    const int lane = tid & 63;
    const int ml   = lane & 15;
    const int g    = lane >> 4;

    __shared__ ushort As0[2 * 4096], As1[2 * 4096];  // 2 bufs x 2 slabs(8KB) = 32KB
    __shared__ ushort Xs[4 * 2048];                  // 16KB: 4 row-regions x 256 chunks

    // A-frag read byte offsets within an 8KB slab (512 chunks), swizzled
    int aoffB[2];
    #pragma unroll
    for (int mi = 0; mi < 2; ++mi)
        aoffB[mi] = swz((32 * wv + 16 * mi + ml) * 4 + g) * 16;
    // B-frag chunk bases: pixel p_ = p0+16nf+ml -> region hl*256 + col*4 + g
    int cbase[7];
    #pragma unroll
    for (int nf = 0; nf < 7; ++nf) {
        const int p_  = p0 + 16 * nf + ml;
        const int hl  = (p_ >= p0 + 56) ? 1 : 0;
        const int col = p_ - 56 * (r0 + hl);
        cbase[nf] = hl * 256 + col * 4 + g;
    }
    // A staging source offsets (2 gloads/thread): position q = k*256+tid holds
    // chunk swz(q) of the 512-chunk half-slab.
    int goffA[2];
    #pragma unroll
    for (int k = 0; k < 2; ++k) {
        const int c = swz(k * 256 + tid);
        goffA[k] = (c >> 2) * 32 + (c & 3) * 8;                 // half-slab elems
    }
    // X row staging: position (rr*256+tid) holds chunk rr*256+ii (R13/R15 proven)
    int xoff;
    {
        const int ii = (tid & 0xC0) | ((tid & 63) ^ (((tid & 63) >> 3) & 7));
        xoff = (ii < 232) ? ((ii >> 2) * CIN + (ii & 3) * 8) : 0;
    }
    const size_t xbase = ((size_t)b * HP + r0) * WP * CIN;
    const ushort* wbase = wb2 + mt * 4096;   // this tile's cout-half of each slab

    f32x4 acc[2][7] = {};

    // stage a 2-slab A group starting at slab S (wraps at 72) into BUF
    #define STAGE_A2(S, BUF)                                                    \
        { _Pragma("unroll")                                                     \
          for (int s = 0; s < 2; ++s) {                                         \
              int _sl = (S) + s; if (_sl >= 72) _sl -= 72;                      \
              const ushort* _src = wbase + (size_t)_sl * 8192;                  \
              _Pragma("unroll")                                                 \
              for (int k = 0; k < 2; ++k)                                       \
                  gload_lds16(_src + goffA[k],                                  \
                              (BUF) + s * 4096 + (k * 256 + wv * 64) * 8);      \
          } }
    #define STAGE_A1(S, BUF)                                                    \
        { int _sl = (S); if (_sl >= 72) _sl -= 72;                              \
          const ushort* _src = wbase + (size_t)_sl * 8192;                      \
          _Pragma("unroll")                                                     \
          for (int k = 0; k < 2; ++k)                                           \
              gload_lds16(_src + goffA[k], (BUF) + (k * 256 + wv * 64) * 8); }
    #define STAGE_XPAIR(RR, CBN)                                                \
        { _Pragma("unroll")                                                     \
          for (int r_ = 0; r_ < 2; ++r_)                                        \
              gload_lds16(xp + xbase + (size_t)((RR) + r_) * WP * CIN           \
                              + (CBN) * 32 + xoff,                              \
                          &Xs[(((RR) + r_) * 256 + wv * 64) * 8]); }

    // prologue: X rows0-3(cb0), G(q0)->As0, G(q1)->As1; full drain; sync
    STAGE_XPAIR(0, 0);
    STAGE_XPAIR(2, 0);
    STAGE_A2(0, As0);
    STAGE_A2(2, As1);
    WAITV(0);
    __syncthreads();

    // phase q taps: q<4 -> {2q, 2q+1}; q4 -> {8}. buffer parity = (cb+q)&1.
    #define PHASE(CB, Q, NTAPS, HWAIT)                                          \
        {                                                                       \
            WAITV(HWAIT);                                                       \
            SCHED_FENCE();                                                      \
            __builtin_amdgcn_s_barrier();                                       \
            SCHED_FENCE();                                                      \
            const ushort* Ab = (((CB) + (Q)) & 1) ? As1 : As0;                  \
            _Pragma("unroll")                                                   \
            for (int tp = 0; tp < (NTAPS); ++tp) {                              \
                const int tap = 2 * (Q) + tp;                                   \
                const int kh = tap / 3, kw = tap - kh * 3;                      \
                short8 av[2], bv[7];                                            \
                _Pragma("unroll")                                               \
                for (int mi = 0; mi < 2; ++mi)                                  \
                    av[mi] = *(const short8*)((const char*)Ab + tp * 8192       \
                                              + aoffB[mi]);                     \
                _Pragma("unroll")                                               \
                for (int nf = 0; nf < 7; ++nf) {                                \
                    const int c = cbase[nf] + kh * 256 + kw * 4;                \
                    bv[nf] = *(const short8*)((const char*)Xs + swz(c) * 16);   \
                }                                                               \
                __builtin_amdgcn_s_setprio(1);                                  \
                _Pragma("unroll")                                               \
                for (int mi = 0; mi < 2; ++mi)                                  \
                    _Pragma("unroll")                                           \
                    for (int nf = 0; nf < 7; ++nf)                              \
                        acc[mi][nf] = __builtin_amdgcn_mfma_f32_16x16x32_bf16(  \
                                          av[mi], bv[nf], acc[mi][nf], 0, 0, 0);\
                __builtin_amdgcn_s_setprio(0);                                  \
            }                                                                   \
            SCHED_FENCE();                                                      \
            __builtin_amdgcn_s_barrier();                                       \
            SCHED_FENCE();                                                      \
        }

    for (int cbp = 0; cbp < 4; ++cbp) {
        #pragma unroll
        for (int hf = 0; hf < 2; ++hf) {
            const int cb  = 2 * cbp + hf;
            const int t0  = 9 * cb;
            const int cbn = (cb < 7) ? cb + 1 : 0;  // cb7: dummy (dead/drained)
            ushort* bufE = ((cb & 1) == 0) ? As0 : As1;  // parity (cb+q)&1 == 0
            ushort* bufO = ((cb & 1) == 0) ? As1 : As0;

            // q0: reads bufE; tail stages G(q2) into bufE
            PHASE(cb, 0, 2, 6);
            STAGE_A2(t0 + 4, bufE);
            SCHED_FENCE();
            // q1: reads bufO; tail stages G(q3) into bufO
            PHASE(cb, 1, 2, 4);
            STAGE_A2(t0 + 6, bufO);
            SCHED_FENCE();
            // q2: reads bufE; tail: X rows01(cb+1) FIRST, then G(q4) into bufE
            PHASE(cb, 2, 2, 4);
            STAGE_XPAIR(0, cbn);
            STAGE_A1(t0 + 8, bufE);
            SCHED_FENCE();
            // q3: reads bufO; tail stages G(next q0) into bufO
            PHASE(cb, 3, 2, 4);
            STAGE_A2(t0 + 9, bufO);
            SCHED_FENCE();
            // q4 (tap 8): reads bufE; tail: X rows23(cb+1), then G(next q1) into bufE
            PHASE(cb, 4, 1, 4);
            STAGE_XPAIR(2, cbn);
            STAGE_A2(t0 + 11, bufE);
            SCHED_FENCE();
        }
    }
    WAITV(0);                              // drain tail dummy stages

    // epilogue: D[row=4g+r][col=ml] (verified R2-R20)
    float* ob = out + (size_t)b * COUT * HW;
    #pragma unroll
    for (int mi = 0; mi < 2; ++mi)
        #pragma unroll
        for (int nf = 0; nf < 7; ++nf)
            #pragma unroll
            for (int r = 0; r < 4; ++r) {
                const int cout_l = mt * 128 + 32 * wv + 16 * mi + 4 * g + r;
                const int p_ = p0 + 16 * nf + ml;
                ob[(size_t)cout_l * HW + p_] = acc[mi][nf][r];
            }
    #undef STAGE_A2
    #undef STAGE_A1
    #undef STAGE_XPAIR
    #undef PHASE
}

// ---------------- R1 fallback (fp32 sparse direct) ----------------

constexpr int WSZ = CIN * 9;
constexpr int NIN = 54 * 54;

__global__ __launch_bounds__(256)
void sparse_conv3x3(const float* __restrict__ x,
                    const float* __restrict__ wgt,
                    float* __restrict__ out) {
    const int bc = blockIdx.x, cout = bc % COUT, b = bc / COUT;
    const int tid = threadIdx.x;
    __shared__ int2 s_ent[WSZ];
    __shared__ unsigned char s_kk[WSZ];
    __shared__ int s_cnt[257];
    const float* wc = wgt + (size_t)cout * WSZ;
    float mv[9]; int cnt = 0;
    #pragma unroll
    for (int i = 0; i < 9; ++i) { mv[i] = wc[tid * 9 + i]; if (mv[i] != 0.0f) cnt++; }
    s_cnt[tid] = cnt; __syncthreads();
    if (tid == 0) { int run = 0; for (int t = 0; t < 256; ++t) { int c = s_cnt[t]; s_cnt[t] = run; run += c; } s_cnt[256] = run; }
    __syncthreads();
    { int pos = s_cnt[tid];
      #pragma unroll
      for (int i = 0; i < 9; ++i) if (mv[i] != 0.0f) {
          const int kh = i / 3, kw = i - kh * 3;
          int2 e; e.x = (tid * HW + (kh - 1) * W + (kw - 1)) * 4; e.y = __float_as_int(mv[i]);
          s_ent[pos] = e; s_kk[pos] = (unsigned char)(kh | (kw << 4)); pos++; } }
    __syncthreads();
    const int nnz = s_cnt[256];
    const char* xb = (const char*)(x + (size_t)b * CIN * HW);
    float* ob = out + (size_t)bc * HW;
    for (int o = tid; o < HW; o += 256) {
        int h, w; bool interior = (o < NIN);
        if (interior) { h = 1 + o / 54; w = 1 + (o - (h - 1) * 54); }
        else { int o2 = o - NIN;
            if (o2 < 56) { h = 0; w = o2; } else if (o2 < 112) { h = 55; w = o2 - 56; }
            else if (o2 < 166) { h = 1 + (o2 - 112); w = 0; } else { h = 1 + (o2 - 166); w = 55; } }
        const char* pb = xb + (size_t)(h * W + w) * 4;
        float acc = 0.0f;
        if (interior) {
            #pragma unroll 4
            for (int e = 0; e < nnz; ++e) { const int2 en = s_ent[e];
                acc = fmaf(__int_as_float(en.y), *(const float*)(pb + en.x), acc); }
        } else {
            const int h1 = h - 1, w1 = w - 1;
            for (int e = 0; e < nnz; ++e) { const int2 en = s_ent[e]; const int kk = s_kk[e];
                const int hh = h1 + (kk & 15), ww = w1 + (kk >> 4);
                if ((unsigned)hh < (unsigned)H && (unsigned)ww < (unsigned)W)
                    acc = fmaf(__int_as_float(en.y), *(const float*)(pb + en.x), acc); } }
        ob[h * W + w] = acc;
    }
}

// ---------------- launch ----------------

extern "C" void kernel_launch(void* const* d_in, const int* in_sizes, int n_in,
                              void* d_out, int out_size, void* d_ws, size_t ws_size,
                              hipStream_t stream) {
    const float* x = (const float*)d_in[0];
    const float* w = (const float*)d_in[1];
    float* out = (float*)d_out;

    if (ws_size >= WS_NEEDED) {
        ushort* xp = (ushort*)d_ws;
        ushort* wbp = xp + XP_ELEMS;
        prep_xp<<<BB * HP, 256, 0, stream>>>(x, xp);
        prep_wb2<<<(int)(WB_ELEMS / 256), 256, 0, stream>>>(w, wbp);
        conv_mfma<<<1792, 256, 0, stream>>>(xp, wbp, out);
    } else {
        sparse_conv3x3<<<BB * COUT, 256, 0, stream>>>(x, w, out);
    }
}